// Round 7
// baseline (2043.218 us; speedup 1.0000x reference)
//
#include <hip/hip_runtime.h>
#include <math.h>

// F=4, T=12, C=512, HID=256, OUT=12
#define NF 48
#define TT 12

typedef __bf16 v8bf __attribute__((ext_vector_type(8)));
typedef float v16f __attribute__((ext_vector_type(16)));

// ---------------- small prep kernels ----------------

__global__ void k_init_deg(float* __restrict__ deg, int n) {
  int i = blockIdx.x * blockDim.x + threadIdx.x;
  if (i < n) deg[i] = 1.0f;
}

__global__ void k_scatter_deg(const int* __restrict__ dst, const float* __restrict__ w,
                              float* __restrict__ deg, int e) {
  int i = blockIdx.x * blockDim.x + threadIdx.x;
  if (i < e) atomicAdd(&deg[dst[i]], w[i]);
}

__global__ void k_dinv(const float* __restrict__ deg, float* __restrict__ dinv, int n) {
  int i = blockIdx.x * blockDim.x + threadIdx.x;
  if (i < n) dinv[i] = rsqrtf(fmaxf(deg[i], 1e-12f));
}

__global__ void k_zeroi(int* __restrict__ p, int n) {
  int i = blockIdx.x * blockDim.x + threadIdx.x;
  if (i < n) p[i] = 0;
}

// ---------------- CSR build (by dst) ----------------

__global__ void k_count(const int* __restrict__ dst, int* __restrict__ cnt, int e) {
  int i = blockIdx.x * blockDim.x + threadIdx.x;
  if (i < e) atomicAdd(&cnt[dst[i]], 1);
}

__global__ void k_scan(const int* __restrict__ cnt, int* __restrict__ offs, int n) {
  __shared__ int s[1024];
  __shared__ int carry;
  int tid = threadIdx.x;
  if (tid == 0) carry = 0;
  __syncthreads();
  for (int base = 0; base < n; base += 1024) {
    int v = (base + tid < n) ? cnt[base + tid] : 0;
    s[tid] = v;
    __syncthreads();
    for (int off = 1; off < 1024; off <<= 1) {
      int t = 0;
      if (tid >= off) t = s[tid - off];
      __syncthreads();
      s[tid] += t;
      __syncthreads();
    }
    if (base + tid < n) offs[base + tid] = carry + s[tid] - v;
    __syncthreads();
    if (tid == 0) carry += s[1023];
    __syncthreads();
  }
  if (tid == 0) offs[n] = carry;
}

__global__ void k_place(const int* __restrict__ src, const int* __restrict__ dst,
                        const float* __restrict__ w, const int* __restrict__ offs,
                        int* __restrict__ fill, int* __restrict__ csrc,
                        float* __restrict__ cw, int e) {
  int i = blockIdx.x * blockDim.x + threadIdx.x;
  if (i >= e) return;
  int d = dst[i];
  int p = offs[d] + atomicAdd(&fill[d], 1);
  csrc[p] = src[i];
  cw[p] = w[i];
}

__global__ void k_gather(const int* __restrict__ offs, const int* __restrict__ csrc,
                         const float* __restrict__ cw, const float* __restrict__ dinv,
                         const float* __restrict__ x, float* __restrict__ Y, int n) {
  int tg = blockIdx.x * blockDim.x + threadIdx.x;
  if (tg >= n * 12) return;
  int i = tg / 12, q = tg % 12;
  float di = dinv[i];
  const float4* x4 = (const float4*)x;
  float4 sv = x4[(size_t)i * 12 + q];
  float ax = di * sv.x, ay = di * sv.y, az = di * sv.z, aw = di * sv.w;
  int e1 = offs[i + 1];
  for (int e = offs[i]; e < e1; e++) {
    int s = csrc[e];
    float wv = cw[e] * dinv[s];
    float4 xv = x4[(size_t)s * 12 + q];
    ax = fmaf(wv, xv.x, ax); ay = fmaf(wv, xv.y, ay);
    az = fmaf(wv, xv.z, az); aw = fmaf(wv, xv.w, aw);
  }
  float4 o = make_float4(di * ax, di * ay, di * az, di * aw);
  ((float4*)Y)[(size_t)i * 12 + q] = o;
}

// ---------------- weight prep: pack into swizzled 128-col tiles ----------------
// layout: [n/128][k/32][ row=n%128 ][ chunk(16B)^ (row&3) ][ e ]
__device__ __forceinline__ size_t packIdx128(int n, int k) {
  int row = n & 127;
  int c = (k & 31) >> 3;
  return (size_t)(n >> 7) * (128 * 512) + (size_t)(k >> 5) * (128 * 32) +
         (size_t)row * 32 + (size_t)((c ^ (row & 3)) << 3) + (k & 7);
}

// [z|r] bottom halves of Wz_l / Wr_l (Nout=1024)
__global__ void k_t_zr(const float* __restrict__ Wzl, const float* __restrict__ Wrl,
                       __bf16* __restrict__ WT) {
  int idx = blockIdx.x * blockDim.x + threadIdx.x;
  if (idx >= 1024 * 512) return;
  int n = idx >> 9, k = idx & 511;
  float v = (n < 512) ? Wzl[(512 + k) * 512 + n] : Wrl[(512 + k) * 512 + (n - 512)];
  WT[packIdx128(n, k)] = (__bf16)v;
}

// Wh_l bottom half (Nout=512)
__global__ void k_t_h(const float* __restrict__ Whl, __bf16* __restrict__ WT) {
  int idx = blockIdx.x * blockDim.x + threadIdx.x;
  if (idx >= 512 * 512) return;
  int n = idx >> 9, k = idx & 511;
  WT[packIdx128(n, k)] = (__bf16)Whl[(512 + k) * 512 + n];
}

// W1 (Nout=256)
__global__ void k_t_1(const float* __restrict__ W1, __bf16* __restrict__ WT) {
  int idx = blockIdx.x * blockDim.x + threadIdx.x;
  if (idx >= 256 * 512) return;
  int n = idx >> 9, k = idx & 511;
  WT[packIdx128(n, k)] = (__bf16)W1[k * 256 + n];
}

__global__ void k_build_eff(const float* __restrict__ Wg, const float* __restrict__ Wl,
                            const float* __restrict__ bg, const float* __restrict__ bl,
                            float* __restrict__ Weff, float* __restrict__ beff,
                            int ostride, int ooff) {
  int idx = blockIdx.x * blockDim.x + threadIdx.x;
  if (idx >= 5 * 512) return;
  int r = idx / 512, c = idx % 512;
  float s = 0.f;
  if (r < 4) {
    for (int k = 0; k < 512; k++) s += Wg[r * 512 + k] * Wl[k * 512 + c];
    Weff[r * ostride + ooff + c] = s;
  } else {
    for (int k = 0; k < 512; k++) s += bg[k] * Wl[k * 512 + c];
    beff[ooff + c] = s + bl[c];
  }
}

__global__ void k_softmax_att(const float* __restrict__ att, float* __restrict__ probs) {
  if (blockIdx.x == 0 && threadIdx.x == 0) {
    float m = -1e30f;
    for (int t = 0; t < TT; t++) m = fmaxf(m, att[t]);
    float e[TT], s = 0.f;
    for (int t = 0; t < TT; t++) { e[t] = expf(att[t] - m); s += e[t]; }
    for (int t = 0; t < TT; t++) probs[t] = e[t] / s;
  }
}

// Wy mini-tiles [n/128][row][k<16]: rows 0..3 = Weff, row4 = beff, rest 0.
// Weff may be null (MODE2: bias only).
__global__ void k_wy(const float* __restrict__ Weff, const float* __restrict__ beff,
                     __bf16* __restrict__ out, int Nout) {
  int idx = blockIdx.x * blockDim.x + threadIdx.x;
  if (idx >= Nout * 16) return;
  int n = idx >> 4, k = idx & 15;
  float v = 0.f;
  if (k < 4) v = Weff ? Weff[k * Nout + n] : 0.f;
  else if (k == 4) v = beff[n];
  out[(size_t)(n >> 7) * 2048 + (size_t)(n & 127) * 16 + k] = (__bf16)v;
}

// Ya[t][n][16]: cols 0..3 = Y[n, f, t], col4 = 1, rest 0.
__global__ void k_ya(const float* __restrict__ Y, __bf16* __restrict__ out, int n) {
  int idx = blockIdx.x * blockDim.x + threadIdx.x;
  if (idx >= TT * n * 16) return;
  int t = idx / (n * 16);
  int r = idx % (n * 16);
  int nn = r >> 4, k = r & 15;
  float v = 0.f;
  if (k < 4) v = Y[(size_t)nn * NF + k * TT + t];
  else if (k == 4) v = 1.f;
  out[idx] = (__bf16)v;
}

// ---------------- MFMA GEMM: m97-style 128x128 tile, 32x32x16 mfma ----------------
// 4 waves 2x2, each wave 64x64 = 2x2 microtiles. BK=32, single LDS buffer,
// 2-barrier loop, register-dbuf staging 1 iter ahead. B pre-swizzled (linear copy),
// A swizzled at store. Y@Weff+beff folded as one extra K=16 mfma (Ay x Wy).
// MODE 0: A=hist[t]. out z (colblk<4) / r (colblk>=4) bf16 row-major, sigmoid.
// MODE 1: A=hist[t]*r (frag-mul). out hist[t+1] = z*hold+(1-z)*tanh.
// MODE 2: A=accRelu. out T1 fp32 relu.
template <int MODE>
__global__ __launch_bounds__(256, (MODE == 1) ? 2 : 3) void k_mm(
    const __bf16* __restrict__ Abf, const __bf16* __restrict__ Bp,
    const __bf16* __restrict__ Rbf, const __bf16* __restrict__ Zbf,
    const __bf16* __restrict__ Ay, const __bf16* __restrict__ Wy,
    float* __restrict__ Ofp, __bf16* __restrict__ Obf, __bf16* __restrict__ ObfR,
    int M, int RB) {
  constexpr int CB = (MODE == 0) ? 8 : (MODE == 1) ? 4 : 2;
  __shared__ __bf16 sA[128 * 32];
  __shared__ __bf16 sB[128 * 32];
  __shared__ __bf16 sR[(MODE == 1) ? 128 * 32 : 64];

  // XCD swizzle: 8 consecutive ids = 8 row-blocks of one col-block; ids differing
  // by 8 (same row, next col) land on the same XCD under round-robin dispatch.
  int s = blockIdx.x;
  int grp = 8 * CB;
  int local = s % grp;
  int rowblk = (s / grp) * 8 + (local & 7);
  int colblk = local >> 3;
  if (rowblk >= RB) return;
  const int row0 = rowblk * 128;

  const int tid = threadIdx.x;
  const int lane = tid & 63, w = tid >> 6;
  const int wr = (w >> 1) * 64, wc = (w & 1) * 64;
  const int l31 = lane & 31, lh = lane >> 5;

  const int sr_ = tid >> 2;     // staging row (0..63, +64 for chunk j=1)
  const int sc_ = tid & 3;      // staging 16B chunk within row
  const __bf16* At = Abf + (size_t)row0 * 512;
  const __bf16* Rt = (MODE == 1) ? (Rbf + (size_t)row0 * 512) : nullptr;
  const __bf16* Bt = Bp + (size_t)colblk * (128 * 512);

  v16f acc[2][2];
#pragma unroll
  for (int i = 0; i < 2; i++)
#pragma unroll
    for (int j = 0; j < 2; j++)
#pragma unroll
      for (int q = 0; q < 16; q++) acc[i][j][q] = 0.f;

  uint4 ra[2][2], rr[2][2], rb[2][2];
  auto gload = [&](int kt, int p) {
#pragma unroll
    for (int j = 0; j < 2; j++) {
      int row = j * 64 + sr_;
      ra[p][j] = *(const uint4*)(At + (size_t)row * 512 + kt * 32 + sc_ * 8);
      if constexpr (MODE == 1)
        rr[p][j] = *(const uint4*)(Rt + (size_t)row * 512 + kt * 32 + sc_ * 8);
      rb[p][j] = *(const uint4*)(Bt + (size_t)kt * 4096 + (size_t)(j * 256 + tid) * 8);
    }
  };
  auto lstore = [&](int p) {
#pragma unroll
    for (int j = 0; j < 2; j++) {
      int row = j * 64 + sr_;
      int off = row * 32 + ((sc_ ^ (row & 3)) << 3);
      *(uint4*)&sA[off] = ra[p][j];
      if constexpr (MODE == 1) *(uint4*)&sR[off] = rr[p][j];
      *(uint4*)&sB[(size_t)(j * 256 + tid) * 8] = rb[p][j];
    }
  };

  gload(0, 0);
  for (int kt = 0; kt < 16; kt++) {
    if (kt) __syncthreads();
    lstore(kt & 1);
    if (kt < 15) gload(kt + 1, (kt + 1) & 1);
    __syncthreads();
#pragma unroll
    for (int ks = 0; ks < 2; ks++) {
      int kc = ks * 2 + lh;
      v8bf af[2], bfr[2];
#pragma unroll
      for (int mi = 0; mi < 2; mi++) {
        int fr = wr + mi * 32 + l31;
        v8bf h = *(const v8bf*)&sA[fr * 32 + ((kc ^ (fr & 3)) << 3)];
        if constexpr (MODE == 1) {
          v8bf r = *(const v8bf*)&sR[fr * 32 + ((kc ^ (fr & 3)) << 3)];
#pragma unroll
          for (int q = 0; q < 8; q++) h[q] = (__bf16)((float)h[q] * (float)r[q]);
        }
        af[mi] = h;
      }
#pragma unroll
      for (int ni = 0; ni < 2; ni++) {
        int fc = wc + ni * 32 + l31;
        bfr[ni] = *(const v8bf*)&sB[fc * 32 + ((kc ^ (fc & 3)) << 3)];
      }
#pragma unroll
      for (int mi = 0; mi < 2; mi++)
#pragma unroll
        for (int ni = 0; ni < 2; ni++)
          acc[mi][ni] = __builtin_amdgcn_mfma_f32_32x32x16_bf16(af[mi], bfr[ni],
                                                               acc[mi][ni], 0, 0, 0);
    }
  }

  // ---- extra K=16 mfma: + Ay(Y_t|1) @ Wy(Weff|beff)
  __syncthreads();
  {
    int row = tid >> 1, half = tid & 1;
    uint4 ya = *(const uint4*)(Ay + (size_t)(row0 + row) * 16 + half * 8);
    uint4 wy = *(const uint4*)(Wy + (size_t)colblk * 2048 + (size_t)row * 16 + half * 8);
    *(uint4*)&sA[row * 16 + half * 8] = ya;
    *(uint4*)&sB[row * 16 + half * 8] = wy;
  }
  __syncthreads();
  {
    v8bf af[2], bfr[2];
#pragma unroll
    for (int mi = 0; mi < 2; mi++)
      af[mi] = *(const v8bf*)&sA[(wr + mi * 32 + l31) * 16 + lh * 8];
#pragma unroll
    for (int ni = 0; ni < 2; ni++)
      bfr[ni] = *(const v8bf*)&sB[(wc + ni * 32 + l31) * 16 + lh * 8];
#pragma unroll
    for (int mi = 0; mi < 2; mi++)
#pragma unroll
      for (int ni = 0; ni < 2; ni++)
        acc[mi][ni] = __builtin_amdgcn_mfma_f32_32x32x16_bf16(af[mi], bfr[ni],
                                                             acc[mi][ni], 0, 0, 0);
  }

  // ---- epilogue. C layout (32x32): col=lane&31, row=(reg&3)+8*(reg>>2)+4*lh
#pragma unroll
  for (int mi = 0; mi < 2; mi++) {
#pragma unroll
    for (int ni = 0; ni < 2; ni++) {
      int cl = wc + ni * 32 + l31;  // col within 128-tile
#pragma unroll
      for (int reg = 0; reg < 16; reg++) {
        int rg = row0 + wr + mi * 32 + (reg & 3) + ((reg >> 2) << 3) + (lh << 2);
        if (rg >= M) continue;
        float v = acc[mi][ni][reg];
        if constexpr (MODE == 0) {
          float sg = 1.f / (1.f + expf(-v));
          if (colblk < 4)
            Obf[(size_t)rg * 512 + colblk * 128 + cl] = (__bf16)sg;
          else
            ObfR[(size_t)rg * 512 + (colblk - 4) * 128 + cl] = (__bf16)sg;
        } else if constexpr (MODE == 1) {
          int cg = colblk * 128 + cl;
          float ht = tanhf(v);
          float z = (float)Zbf[(size_t)rg * 512 + cg];
          float hold = (float)Abf[(size_t)rg * 512 + cg];
          float hn = z * hold + (1.f - z) * ht;
          Obf[(size_t)rg * 512 + cg] = (__bf16)hn;
        } else {
          Ofp[(size_t)rg * 256 + colblk * 128 + cl] = fmaxf(v, 0.f);
        }
      }
    }
  }
}

// acc[i,c] = sum_t probs[t] * hist[t+1][i,c];  accRelu = bf16(relu(acc))
__global__ void k_acc(const __bf16* __restrict__ hist, const float* __restrict__ probs,
                      float* __restrict__ acc, __bf16* __restrict__ accRelu, int n) {
  int idx = blockIdx.x * blockDim.x + threadIdx.x;
  if (idx >= n * 64) return;
  size_t off = (size_t)idx * 8;
  size_t S = (size_t)n * 512;
  float s[8] = {0, 0, 0, 0, 0, 0, 0, 0};
#pragma unroll
  for (int t = 0; t < TT; t++) {
    float p = probs[t];
    v8bf h = *(const v8bf*)(hist + (size_t)(t + 1) * S + off);
#pragma unroll
    for (int j = 0; j < 8; j++) s[j] = fmaf(p, (float)h[j], s[j]);
  }
  *(float4*)(acc + off) = make_float4(s[0], s[1], s[2], s[3]);
  *(float4*)(acc + off + 4) = make_float4(s[4], s[5], s[6], s[7]);
  v8bf rl;
#pragma unroll
  for (int j = 0; j < 8; j++) rl[j] = (__bf16)fmaxf(s[j], 0.f);
  *(v8bf*)(accRelu + off) = rl;
}

__global__ void k_head2(const float* __restrict__ T1, const float* __restrict__ W2,
                        const float* __restrict__ b2, float* __restrict__ out0, int M) {
  int idx = blockIdx.x * blockDim.x + threadIdx.x;
  if (idx >= M * 12) return;
  int i = idx / 12, c = idx % 12;
  const float* tr = T1 + (size_t)i * 256;
  float s = b2[c];
  for (int k = 0; k < 256; k++) s = fmaf(tr[k], W2[k * 12 + c], s);
  out0[idx] = s;
}

// ---------------- launch ----------------

extern "C" void kernel_launch(void* const* d_in, const int* in_sizes, int n_in,
                              void* d_out, int out_size, void* d_ws, size_t ws_size,
                              hipStream_t stream) {
  const float* x   = (const float*)d_in[0];
  const int*   ei  = (const int*)d_in[1];
  const float* ea  = (const float*)d_in[2];
  const float* att = (const float*)d_in[3];
  const float* Wzg = (const float*)d_in[4];  const float* bzg = (const float*)d_in[5];
  const float* Wzl = (const float*)d_in[6];  const float* bzl = (const float*)d_in[7];
  const float* Wrg = (const float*)d_in[8];  const float* brg = (const float*)d_in[9];
  const float* Wrl = (const float*)d_in[10]; const float* brl = (const float*)d_in[11];
  const float* Whg = (const float*)d_in[12]; const float* bhg = (const float*)d_in[13];
  const float* Whl = (const float*)d_in[14]; const float* bhl = (const float*)d_in[15];
  const float* W1  = (const float*)d_in[16]; const float* b1  = (const float*)d_in[17];
  const float* W2  = (const float*)d_in[18]; const float* b2  = (const float*)d_in[19];

  const int N = in_sizes[0] / NF;
  const int E = in_sizes[1] / 2;
  const int* srcI = ei;
  const int* dstI = ei + E;

  float* out0 = (float*)d_out;                   // [N,12]
  float* accO = (float*)d_out + (size_t)N * 12;  // [N,512] = H_accum (output 1)

  char* wp = (char*)d_ws;
  auto carve = [&](size_t bytes) -> void* {
    void* p = (void*)wp;
    wp += (bytes + 255) & ~(size_t)255;
    return p;
  };
  float*  deg     = (float*)carve((size_t)N * 4);
  float*  dinv    = (float*)carve((size_t)N * 4);
  float*  probs   = (float*)carve(64);
  float*  Y       = (float*)carve((size_t)N * NF * 4);
  __bf16* WzrP    = (__bf16*)carve((size_t)1024 * 512 * 2);
  __bf16* WhP     = (__bf16*)carve((size_t)512 * 512 * 2);
  __bf16* W1P     = (__bf16*)carve((size_t)256 * 512 * 2);
  float*  Wzr_eff = (float*)carve((size_t)4 * 1024 * 4);
  float*  bzr_eff = (float*)carve((size_t)1024 * 4);
  float*  Wh_eff  = (float*)carve((size_t)4 * 512 * 4);
  float*  bh_eff  = (float*)carve((size_t)512 * 4);
  __bf16* hist    = (__bf16*)carve((size_t)(TT + 1) * N * 512 * 2);  // H_0..H_12 bf16
  __bf16* Zbf     = (__bf16*)carve((size_t)N * 512 * 2);
  __bf16* Rbf     = (__bf16*)carve((size_t)N * 512 * 2);
  __bf16* accRelu = (__bf16*)carve((size_t)N * 512 * 2);
  float*  T1      = (float*)carve((size_t)N * 256 * 4);
  __bf16* Ya      = (__bf16*)carve((size_t)TT * N * 16 * 2);
  __bf16* WyZR    = (__bf16*)carve((size_t)1024 * 16 * 2);
  __bf16* WyH     = (__bf16*)carve((size_t)512 * 16 * 2);
  __bf16* Wy1     = (__bf16*)carve((size_t)256 * 16 * 2);
  int*    cnt     = (int*)carve((size_t)2 * N * 4);  // cnt[N] + fill[N] contiguous
  int*    fill    = cnt + N;
  int*    offs    = (int*)carve((size_t)(N + 1) * 4);
  int*    csrc    = (int*)carve((size_t)E * 4);
  float*  cw      = (float*)carve((size_t)E * 4);
  (void)carve(512 * 1024);  // tail pad: OOB tile reads past last A-source stay in ws
  (void)ws_size; (void)n_in; (void)out_size;

  const int TPB = 256;
  auto cdiv = [](int a, int b) { return (a + b - 1) / b; };
  const size_t S = (size_t)N * 512;

  // degree + normalization
  k_init_deg<<<cdiv(N, TPB), TPB, 0, stream>>>(deg, N);
  k_scatter_deg<<<cdiv(E, TPB), TPB, 0, stream>>>(dstI, ea, deg, E);
  k_dinv<<<cdiv(N, TPB), TPB, 0, stream>>>(deg, dinv, N);

  // CSR by dst, then gather Y = Ahat @ X
  k_zeroi<<<cdiv(2 * N, TPB), TPB, 0, stream>>>(cnt, 2 * N);
  k_count<<<cdiv(E, TPB), TPB, 0, stream>>>(dstI, cnt, E);
  k_scan<<<1, 1024, 0, stream>>>(cnt, offs, N);
  k_place<<<cdiv(E, TPB), TPB, 0, stream>>>(srcI, dstI, ea, offs, fill, csrc, cw, E);
  k_gather<<<cdiv(N * 12, TPB), TPB, 0, stream>>>(offs, csrc, cw, dinv, x, Y, N);

  // weight prep
  k_t_zr<<<cdiv(1024 * 512, TPB), TPB, 0, stream>>>(Wzl, Wrl, WzrP);
  k_t_h<<<cdiv(512 * 512, TPB), TPB, 0, stream>>>(Whl, WhP);
  k_t_1<<<cdiv(256 * 512, TPB), TPB, 0, stream>>>(W1, W1P);
  k_build_eff<<<cdiv(5 * 512, TPB), TPB, 0, stream>>>(Wzg, Wzl, bzg, bzl, Wzr_eff, bzr_eff, 1024, 0);
  k_build_eff<<<cdiv(5 * 512, TPB), TPB, 0, stream>>>(Wrg, Wrl, brg, brl, Wzr_eff, bzr_eff, 1024, 512);
  k_build_eff<<<cdiv(5 * 512, TPB), TPB, 0, stream>>>(Whg, Whl, bhg, bhl, Wh_eff, bh_eff, 512, 0);
  k_softmax_att<<<1, 64, 0, stream>>>(att, probs);
  k_wy<<<cdiv(1024 * 16, TPB), TPB, 0, stream>>>(Wzr_eff, bzr_eff, WyZR, 1024);
  k_wy<<<cdiv(512 * 16, TPB), TPB, 0, stream>>>(Wh_eff, bh_eff, WyH, 512);
  k_wy<<<cdiv(256 * 16, TPB), TPB, 0, stream>>>(nullptr, b1, Wy1, 256);
  k_ya<<<cdiv(TT * N * 16, TPB), TPB, 0, stream>>>(Y, Ya, N);

  // hist slot 0 = H_0 = 0
  k_zeroi<<<cdiv(N * 256, TPB), TPB, 0, stream>>>((int*)hist, N * 256);

  const int RB = cdiv(N, 128);         // 79 row blocks
  const int nGrp = cdiv(RB, 8);        // 10 padded groups
  for (int t = 0; t < TT; t++) {
    const __bf16* Hbt = hist + (size_t)t * S;
    __bf16* Hbn = hist + (size_t)(t + 1) * S;
    const __bf16* Yat = Ya + (size_t)t * N * 16;
    k_mm<0><<<64 * nGrp, 256, 0, stream>>>(Hbt, WzrP, nullptr, nullptr, Yat, WyZR,
                                           nullptr, Zbf, Rbf, N, RB);
    k_mm<1><<<32 * nGrp, 256, 0, stream>>>(Hbt, WhP, Rbf, Zbf, Yat, WyH,
                                           nullptr, Hbn, nullptr, N, RB);
  }

  // H_accum = sum_t p_t H_{t+1}; head
  k_acc<<<cdiv(N * 64, TPB), TPB, 0, stream>>>(hist, probs, accO, accRelu, N);
  k_mm<2><<<16 * nGrp, 256, 0, stream>>>(accRelu, W1P, nullptr, nullptr, Ya, Wy1,
                                         T1, nullptr, nullptr, N, RB);
  k_head2<<<cdiv(N * 12, TPB), TPB, 0, stream>>>(T1, W2, b2, out0, N);
}

// Round 8
// 1033.383 us; speedup vs baseline: 1.9772x; 1.9772x over previous
//
#include <hip/hip_runtime.h>
#include <math.h>

// F=4, T=12, C=512, HID=256, OUT=12
#define NF 48
#define TT 12

typedef __bf16 v8bf __attribute__((ext_vector_type(8)));
typedef float v16f __attribute__((ext_vector_type(16)));

// ---------------- small prep kernels ----------------

__global__ void k_init_deg(float* __restrict__ deg, int n) {
  int i = blockIdx.x * blockDim.x + threadIdx.x;
  if (i < n) deg[i] = 1.0f;
}

__global__ void k_scatter_deg(const int* __restrict__ dst, const float* __restrict__ w,
                              float* __restrict__ deg, int e) {
  int i = blockIdx.x * blockDim.x + threadIdx.x;
  if (i < e) atomicAdd(&deg[dst[i]], w[i]);
}

__global__ void k_dinv(const float* __restrict__ deg, float* __restrict__ dinv, int n) {
  int i = blockIdx.x * blockDim.x + threadIdx.x;
  if (i < n) dinv[i] = rsqrtf(fmaxf(deg[i], 1e-12f));
}

__global__ void k_zeroi(int* __restrict__ p, int n) {
  int i = blockIdx.x * blockDim.x + threadIdx.x;
  if (i < n) p[i] = 0;
}

// ---------------- CSR build (by dst) ----------------

__global__ void k_count(const int* __restrict__ dst, int* __restrict__ cnt, int e) {
  int i = blockIdx.x * blockDim.x + threadIdx.x;
  if (i < e) atomicAdd(&cnt[dst[i]], 1);
}

__global__ void k_scan(const int* __restrict__ cnt, int* __restrict__ offs, int n) {
  __shared__ int s[1024];
  __shared__ int carry;
  int tid = threadIdx.x;
  if (tid == 0) carry = 0;
  __syncthreads();
  for (int base = 0; base < n; base += 1024) {
    int v = (base + tid < n) ? cnt[base + tid] : 0;
    s[tid] = v;
    __syncthreads();
    for (int off = 1; off < 1024; off <<= 1) {
      int t = 0;
      if (tid >= off) t = s[tid - off];
      __syncthreads();
      s[tid] += t;
      __syncthreads();
    }
    if (base + tid < n) offs[base + tid] = carry + s[tid] - v;
    __syncthreads();
    if (tid == 0) carry += s[1023];
    __syncthreads();
  }
  if (tid == 0) offs[n] = carry;
}

__global__ void k_place(const int* __restrict__ src, const int* __restrict__ dst,
                        const float* __restrict__ w, const int* __restrict__ offs,
                        int* __restrict__ fill, int* __restrict__ csrc,
                        float* __restrict__ cw, int e) {
  int i = blockIdx.x * blockDim.x + threadIdx.x;
  if (i >= e) return;
  int d = dst[i];
  int p = offs[d] + atomicAdd(&fill[d], 1);
  csrc[p] = src[i];
  cw[p] = w[i];
}

__global__ void k_gather(const int* __restrict__ offs, const int* __restrict__ csrc,
                         const float* __restrict__ cw, const float* __restrict__ dinv,
                         const float* __restrict__ x, float* __restrict__ Y, int n) {
  int tg = blockIdx.x * blockDim.x + threadIdx.x;
  if (tg >= n * 12) return;
  int i = tg / 12, q = tg % 12;
  float di = dinv[i];
  const float4* x4 = (const float4*)x;
  float4 sv = x4[(size_t)i * 12 + q];
  float ax = di * sv.x, ay = di * sv.y, az = di * sv.z, aw = di * sv.w;
  int e1 = offs[i + 1];
  for (int e = offs[i]; e < e1; e++) {
    int s = csrc[e];
    float wv = cw[e] * dinv[s];
    float4 xv = x4[(size_t)s * 12 + q];
    ax = fmaf(wv, xv.x, ax); ay = fmaf(wv, xv.y, ay);
    az = fmaf(wv, xv.z, az); aw = fmaf(wv, xv.w, aw);
  }
  float4 o = make_float4(di * ax, di * ay, di * az, di * aw);
  ((float4*)Y)[(size_t)i * 12 + q] = o;
}

// ---------------- weight prep: pack into swizzled 128-col tiles ----------------
// layout: [n/128][k/32][ row=n%128 ][ chunk(16B)^(row&3) ][ e ]   (verified R7)
__device__ __forceinline__ size_t packIdx128(int n, int k) {
  int row = n & 127;
  int c = (k & 31) >> 3;
  return (size_t)(n >> 7) * (128 * 512) + (size_t)(k >> 5) * (128 * 32) +
         (size_t)row * 32 + (size_t)((c ^ (row & 3)) << 3) + (k & 7);
}

__global__ void k_t_zr(const float* __restrict__ Wzl, const float* __restrict__ Wrl,
                       __bf16* __restrict__ WT) {
  int idx = blockIdx.x * blockDim.x + threadIdx.x;
  if (idx >= 1024 * 512) return;
  int n = idx >> 9, k = idx & 511;
  float v = (n < 512) ? Wzl[(512 + k) * 512 + n] : Wrl[(512 + k) * 512 + (n - 512)];
  WT[packIdx128(n, k)] = (__bf16)v;
}

__global__ void k_t_h(const float* __restrict__ Whl, __bf16* __restrict__ WT) {
  int idx = blockIdx.x * blockDim.x + threadIdx.x;
  if (idx >= 512 * 512) return;
  int n = idx >> 9, k = idx & 511;
  WT[packIdx128(n, k)] = (__bf16)Whl[(512 + k) * 512 + n];
}

__global__ void k_t_1(const float* __restrict__ W1, __bf16* __restrict__ WT) {
  int idx = blockIdx.x * blockDim.x + threadIdx.x;
  if (idx >= 256 * 512) return;
  int n = idx >> 9, k = idx & 511;
  WT[packIdx128(n, k)] = (__bf16)W1[k * 256 + n];
}

__global__ void k_build_eff(const float* __restrict__ Wg, const float* __restrict__ Wl,
                            const float* __restrict__ bg, const float* __restrict__ bl,
                            float* __restrict__ Weff, float* __restrict__ beff,
                            int ostride, int ooff) {
  int idx = blockIdx.x * blockDim.x + threadIdx.x;
  if (idx >= 5 * 512) return;
  int r = idx / 512, c = idx % 512;
  float s = 0.f;
  if (r < 4) {
    for (int k = 0; k < 512; k++) s += Wg[r * 512 + k] * Wl[k * 512 + c];
    Weff[r * ostride + ooff + c] = s;
  } else {
    for (int k = 0; k < 512; k++) s += bg[k] * Wl[k * 512 + c];
    beff[ooff + c] = s + bl[c];
  }
}

__global__ void k_softmax_att(const float* __restrict__ att, float* __restrict__ probs) {
  if (blockIdx.x == 0 && threadIdx.x == 0) {
    float m = -1e30f;
    for (int t = 0; t < TT; t++) m = fmaxf(m, att[t]);
    float e[TT], s = 0.f;
    for (int t = 0; t < TT; t++) { e[t] = expf(att[t] - m); s += e[t]; }
    for (int t = 0; t < TT; t++) probs[t] = e[t] / s;
  }
}

// Wy mini-tiles [n/128][row][k<16]: rows 0..3 = Weff, row4 = beff, rest 0.
__global__ void k_wy(const float* __restrict__ Weff, const float* __restrict__ beff,
                     __bf16* __restrict__ out, int Nout) {
  int idx = blockIdx.x * blockDim.x + threadIdx.x;
  if (idx >= Nout * 16) return;
  int n = idx >> 4, k = idx & 15;
  float v = 0.f;
  if (k < 4) v = Weff ? Weff[k * Nout + n] : 0.f;
  else if (k == 4) v = beff[n];
  out[(size_t)(n >> 7) * 2048 + (size_t)(n & 127) * 16 + k] = (__bf16)v;
}

// Ya[t][n][16]: cols 0..3 = Y[n, f, t], col4 = 1, rest 0.
__global__ void k_ya(const float* __restrict__ Y, __bf16* __restrict__ out, int n) {
  int idx = blockIdx.x * blockDim.x + threadIdx.x;
  if (idx >= TT * n * 16) return;
  int t = idx / (n * 16);
  int r = idx % (n * 16);
  int nn = r >> 4, k = r & 15;
  float v = 0.f;
  if (k < 4) v = Y[(size_t)nn * NF + k * TT + t];
  else if (k == 4) v = 1.f;
  out[idx] = (__bf16)v;
}

// ---------------- MFMA GEMM: 64x128 tile, 32x32x16 mfma, fully unrolled ----------------
// 4 waves 2x2 over (64 rows, 128 cols); wave = 32 rows x 64 cols = 2 mfma/k16.
// BK=32, 16 fully-unrolled iterations, single LDS buffer, 2 barriers/iter,
// named staging regs (no runtime-indexed arrays -> no scratch).
// Y@Weff+beff folded as one extra K=16 mfma. bf16 outputs staged via LDS for
// coalesced dwordx4 stores. XCD swizzle: same-row col-blocks share an XCD.
template <int MODE>
__global__ __launch_bounds__(256, 4) void k_mm(
    const __bf16* __restrict__ Abf, const __bf16* __restrict__ Bp,
    const __bf16* __restrict__ Rbf, const __bf16* __restrict__ Zbf,
    const __bf16* __restrict__ Ay, const __bf16* __restrict__ Wy,
    float* __restrict__ Ofp, __bf16* __restrict__ Obf, __bf16* __restrict__ ObfR,
    int M, int RB) {
  constexpr int CB = (MODE == 0) ? 8 : (MODE == 1) ? 4 : 2;
  __shared__ __bf16 smem[8192];  // 16 KB: sA 2048 | sB 4096 | sR 2048 ; reused as sOut
  __bf16* sA = smem;
  __bf16* sB = smem + 2048;
  __bf16* sR = smem + 6144;

  int s = blockIdx.x;
  int grp = 8 * CB;
  int local = s % grp;
  int rowblk = (s / grp) * 8 + (local & 7);
  int colblk = local >> 3;
  if (rowblk >= RB) return;
  const int row0 = rowblk * 64;

  const int tid = threadIdx.x;
  const int lane = tid & 63, w = tid >> 6;
  const int wr = (w >> 1) * 32, wc = (w & 1) * 64;
  const int l31 = lane & 31, lh = lane >> 5;

  // staging coords: A 64 rows x 32 k -> 1 x 16B/thread; B 128 x 32 -> 2 x 16B/thread
  const int ar = tid >> 2, ac = tid & 3;
  const __bf16* At = Abf + (size_t)(row0 + ar) * 512 + ac * 8;
  const __bf16* Rt = Rbf + (size_t)(row0 + ar) * 512 + ac * 8;  // MODE1 only
  const __bf16* Bt = Bp + (size_t)colblk * (128 * 512);
  const int aoff = ar * 32 + ((ac ^ (ar & 3)) << 3);

  v16f acc[2];
#pragma unroll
  for (int j = 0; j < 2; j++)
#pragma unroll
    for (int q = 0; q < 16; q++) acc[j][q] = 0.f;

  uint4 ra, rr, rb0, rb1;
  rr = make_uint4(0, 0, 0, 0);

  // preload kt=0
  ra = *(const uint4*)(At);
  if constexpr (MODE == 1) rr = *(const uint4*)(Rt);
  rb0 = *(const uint4*)(Bt + (size_t)tid * 8);
  rb1 = *(const uint4*)(Bt + (size_t)(256 + tid) * 8);

#pragma unroll
  for (int kt = 0; kt < 16; kt++) {
    if (kt) __syncthreads();
    *(uint4*)&sA[aoff] = ra;
    if constexpr (MODE == 1) *(uint4*)&sR[aoff] = rr;
    *(uint4*)&sB[(size_t)tid * 8] = rb0;
    *(uint4*)&sB[(size_t)(256 + tid) * 8] = rb1;
    if (kt < 15) {
      ra = *(const uint4*)(At + (kt + 1) * 32);
      if constexpr (MODE == 1) rr = *(const uint4*)(Rt + (kt + 1) * 32);
      rb0 = *(const uint4*)(Bt + (size_t)(kt + 1) * 4096 + (size_t)tid * 8);
      rb1 = *(const uint4*)(Bt + (size_t)(kt + 1) * 4096 + (size_t)(256 + tid) * 8);
    }
    __syncthreads();
#pragma unroll
    for (int ks = 0; ks < 2; ks++) {
      int kc = ks * 2 + lh;
      int fr = wr + l31;
      v8bf a = *(const v8bf*)&sA[fr * 32 + ((kc ^ (fr & 3)) << 3)];
      if constexpr (MODE == 1) {
        v8bf r = *(const v8bf*)&sR[fr * 32 + ((kc ^ (fr & 3)) << 3)];
#pragma unroll
        for (int q = 0; q < 8; q++) a[q] = (__bf16)((float)a[q] * (float)r[q]);
      }
#pragma unroll
      for (int ni = 0; ni < 2; ni++) {
        int fc = wc + ni * 32 + l31;
        v8bf b = *(const v8bf*)&sB[fc * 32 + ((kc ^ (fc & 3)) << 3)];
        acc[ni] = __builtin_amdgcn_mfma_f32_32x32x16_bf16(a, b, acc[ni], 0, 0, 0);
      }
    }
  }

  // ---- extra K=16 mfma: + Ay(Y_t|1) @ Wy(Weff|beff)
  __syncthreads();
  {
    int row = tid >> 1, half = tid & 1;
    if (tid < 128)
      *(uint4*)&sA[row * 16 + half * 8] =
          *(const uint4*)(Ay + (size_t)(row0 + row) * 16 + half * 8);
    *(uint4*)&sB[row * 16 + half * 8] =
        *(const uint4*)(Wy + (size_t)colblk * 2048 + (size_t)row * 16 + half * 8);
  }
  __syncthreads();
  {
    v8bf a = *(const v8bf*)&sA[(wr + l31) * 16 + lh * 8];
#pragma unroll
    for (int ni = 0; ni < 2; ni++) {
      v8bf b = *(const v8bf*)&sB[(wc + ni * 32 + l31) * 16 + lh * 8];
      acc[ni] = __builtin_amdgcn_mfma_f32_32x32x16_bf16(a, b, acc[ni], 0, 0, 0);
    }
  }
  __syncthreads();  // before reusing smem as sOut

  // ---- epilogue. C layout (32x32): col=lane&31, row=(reg&3)+8*(reg>>2)+4*lh
  if constexpr (MODE == 2) {
#pragma unroll
    for (int ni = 0; ni < 2; ni++) {
      int cl = wc + ni * 32 + l31;
#pragma unroll
      for (int reg = 0; reg < 16; reg++) {
        int rg = row0 + wr + (reg & 3) + ((reg >> 2) << 3) + (lh << 2);
        if (rg >= M) continue;
        Ofp[(size_t)rg * 256 + colblk * 128 + cl] = fmaxf(acc[ni][reg], 0.f);
      }
    }
  } else {
    // activation -> LDS (64x128 bf16 = 16 KB), then coalesced dwordx4 stores
#pragma unroll
    for (int ni = 0; ni < 2; ni++) {
      int cl = wc + ni * 32 + l31;
#pragma unroll
      for (int reg = 0; reg < 16; reg++) {
        int lr = wr + (reg & 3) + ((reg >> 2) << 3) + (lh << 2);
        float v = acc[ni][reg];
        float o;
        if constexpr (MODE == 0) {
          o = 1.f / (1.f + expf(-v));
        } else {
          int rg = row0 + lr;
          int cg = colblk * 128 + cl;
          float ht = tanhf(v);
          float z = (float)Zbf[(size_t)rg * 512 + cg];
          float hold = (float)Abf[(size_t)rg * 512 + cg];
          o = z * hold + (1.f - z) * ht;
        }
        smem[lr * 128 + cl] = (__bf16)o;
      }
    }
    __syncthreads();
    int row = tid >> 2, seg = (tid & 3) * 32;
    int rg = row0 + row;
    if (rg < M) {
      __bf16* dst;
      int cof;
      if constexpr (MODE == 0) {
        dst = (colblk < 4) ? Obf : ObfR;
        cof = (colblk & 3) * 128;
      } else {
        dst = Obf;
        cof = colblk * 128;
      }
#pragma unroll
      for (int q = 0; q < 4; q++) {
        uint4 v = *(const uint4*)&smem[row * 128 + seg + q * 8];
        *(uint4*)(dst + (size_t)rg * 512 + cof + seg + q * 8) = v;
      }
    }
  }
}

// acc[i,c] = sum_t probs[t] * hist[t+1][i,c];  accRelu = bf16(relu(acc))
__global__ void k_acc(const __bf16* __restrict__ hist, const float* __restrict__ probs,
                      float* __restrict__ acc, __bf16* __restrict__ accRelu, int n) {
  int idx = blockIdx.x * blockDim.x + threadIdx.x;
  if (idx >= n * 64) return;
  size_t off = (size_t)idx * 8;
  size_t S = (size_t)n * 512;
  float s[8] = {0, 0, 0, 0, 0, 0, 0, 0};
#pragma unroll
  for (int t = 0; t < TT; t++) {
    float p = probs[t];
    v8bf h = *(const v8bf*)(hist + (size_t)(t + 1) * S + off);
#pragma unroll
    for (int j = 0; j < 8; j++) s[j] = fmaf(p, (float)h[j], s[j]);
  }
  *(float4*)(acc + off) = make_float4(s[0], s[1], s[2], s[3]);
  *(float4*)(acc + off + 4) = make_float4(s[4], s[5], s[6], s[7]);
  v8bf rl;
#pragma unroll
  for (int j = 0; j < 8; j++) rl[j] = (__bf16)fmaxf(s[j], 0.f);
  *(v8bf*)(accRelu + off) = rl;
}

__global__ void k_head2(const float* __restrict__ T1, const float* __restrict__ W2,
                        const float* __restrict__ b2, float* __restrict__ out0, int M) {
  int idx = blockIdx.x * blockDim.x + threadIdx.x;
  if (idx >= M * 12) return;
  int i = idx / 12, c = idx % 12;
  const float* tr = T1 + (size_t)i * 256;
  float s = b2[c];
  for (int k = 0; k < 256; k++) s = fmaf(tr[k], W2[k * 12 + c], s);
  out0[idx] = s;
}

// ---------------- launch ----------------

extern "C" void kernel_launch(void* const* d_in, const int* in_sizes, int n_in,
                              void* d_out, int out_size, void* d_ws, size_t ws_size,
                              hipStream_t stream) {
  const float* x   = (const float*)d_in[0];
  const int*   ei  = (const int*)d_in[1];
  const float* ea  = (const float*)d_in[2];
  const float* att = (const float*)d_in[3];
  const float* Wzg = (const float*)d_in[4];  const float* bzg = (const float*)d_in[5];
  const float* Wzl = (const float*)d_in[6];  const float* bzl = (const float*)d_in[7];
  const float* Wrg = (const float*)d_in[8];  const float* brg = (const float*)d_in[9];
  const float* Wrl = (const float*)d_in[10]; const float* brl = (const float*)d_in[11];
  const float* Whg = (const float*)d_in[12]; const float* bhg = (const float*)d_in[13];
  const float* Whl = (const float*)d_in[14]; const float* bhl = (const float*)d_in[15];
  const float* W1  = (const float*)d_in[16]; const float* b1  = (const float*)d_in[17];
  const float* W2  = (const float*)d_in[18]; const float* b2  = (const float*)d_in[19];

  const int N = in_sizes[0] / NF;
  const int E = in_sizes[1] / 2;
  const int* srcI = ei;
  const int* dstI = ei + E;

  float* out0 = (float*)d_out;                   // [N,12]
  float* accO = (float*)d_out + (size_t)N * 12;  // [N,512] = H_accum (output 1)

  char* wp = (char*)d_ws;
  auto carve = [&](size_t bytes) -> void* {
    void* p = (void*)wp;
    wp += (bytes + 255) & ~(size_t)255;
    return p;
  };
  float*  deg     = (float*)carve((size_t)N * 4);
  float*  dinv    = (float*)carve((size_t)N * 4);
  float*  probs   = (float*)carve(64);
  float*  Y       = (float*)carve((size_t)N * NF * 4);
  __bf16* WzrP    = (__bf16*)carve((size_t)1024 * 512 * 2);
  __bf16* WhP     = (__bf16*)carve((size_t)512 * 512 * 2);
  __bf16* W1P     = (__bf16*)carve((size_t)256 * 512 * 2);
  float*  Wzr_eff = (float*)carve((size_t)4 * 1024 * 4);
  float*  bzr_eff = (float*)carve((size_t)1024 * 4);
  float*  Wh_eff  = (float*)carve((size_t)4 * 512 * 4);
  float*  bh_eff  = (float*)carve((size_t)512 * 4);
  __bf16* hist    = (__bf16*)carve((size_t)(TT + 1) * N * 512 * 2);  // H_0..H_12 bf16
  __bf16* Zbf     = (__bf16*)carve((size_t)N * 512 * 2);
  __bf16* Rbf     = (__bf16*)carve((size_t)N * 512 * 2);
  __bf16* accRelu = (__bf16*)carve((size_t)N * 512 * 2);
  float*  T1      = (float*)carve((size_t)N * 256 * 4);
  __bf16* Ya      = (__bf16*)carve((size_t)TT * N * 16 * 2);
  __bf16* WyZR    = (__bf16*)carve((size_t)1024 * 16 * 2);
  __bf16* WyH     = (__bf16*)carve((size_t)512 * 16 * 2);
  __bf16* Wy1     = (__bf16*)carve((size_t)256 * 16 * 2);
  int*    cnt     = (int*)carve((size_t)2 * N * 4);  // cnt[N] + fill[N] contiguous
  int*    fill    = cnt + N;
  int*    offs    = (int*)carve((size_t)(N + 1) * 4);
  int*    csrc    = (int*)carve((size_t)E * 4);
  float*  cw      = (float*)carve((size_t)E * 4);
  (void)carve(512 * 1024);  // tail pad: OOB tile reads stay inside ws
  (void)ws_size; (void)n_in; (void)out_size;

  const int TPB = 256;
  auto cdiv = [](int a, int b) { return (a + b - 1) / b; };
  const size_t S = (size_t)N * 512;

  // degree + normalization
  k_init_deg<<<cdiv(N, TPB), TPB, 0, stream>>>(deg, N);
  k_scatter_deg<<<cdiv(E, TPB), TPB, 0, stream>>>(dstI, ea, deg, E);
  k_dinv<<<cdiv(N, TPB), TPB, 0, stream>>>(deg, dinv, N);

  // CSR by dst, then gather Y = Ahat @ X
  k_zeroi<<<cdiv(2 * N, TPB), TPB, 0, stream>>>(cnt, 2 * N);
  k_count<<<cdiv(E, TPB), TPB, 0, stream>>>(dstI, cnt, E);
  k_scan<<<1, 1024, 0, stream>>>(cnt, offs, N);
  k_place<<<cdiv(E, TPB), TPB, 0, stream>>>(srcI, dstI, ea, offs, fill, csrc, cw, E);
  k_gather<<<cdiv(N * 12, TPB), TPB, 0, stream>>>(offs, csrc, cw, dinv, x, Y, N);

  // weight prep
  k_t_zr<<<cdiv(1024 * 512, TPB), TPB, 0, stream>>>(Wzl, Wrl, WzrP);
  k_t_h<<<cdiv(512 * 512, TPB), TPB, 0, stream>>>(Whl, WhP);
  k_t_1<<<cdiv(256 * 512, TPB), TPB, 0, stream>>>(W1, W1P);
  k_build_eff<<<cdiv(5 * 512, TPB), TPB, 0, stream>>>(Wzg, Wzl, bzg, bzl, Wzr_eff, bzr_eff, 1024, 0);
  k_build_eff<<<cdiv(5 * 512, TPB), TPB, 0, stream>>>(Wrg, Wrl, brg, brl, Wzr_eff, bzr_eff, 1024, 512);
  k_build_eff<<<cdiv(5 * 512, TPB), TPB, 0, stream>>>(Whg, Whl, bhg, bhl, Wh_eff, bh_eff, 512, 0);
  k_softmax_att<<<1, 64, 0, stream>>>(att, probs);
  k_wy<<<cdiv(1024 * 16, TPB), TPB, 0, stream>>>(Wzr_eff, bzr_eff, WyZR, 1024);
  k_wy<<<cdiv(512 * 16, TPB), TPB, 0, stream>>>(Wh_eff, bh_eff, WyH, 512);
  k_wy<<<cdiv(256 * 16, TPB), TPB, 0, stream>>>(nullptr, b1, Wy1, 256);
  k_ya<<<cdiv(TT * N * 16, TPB), TPB, 0, stream>>>(Y, Ya, N);

  // hist slot 0 = H_0 = 0
  k_zeroi<<<cdiv(N * 256, TPB), TPB, 0, stream>>>((int*)hist, N * 256);

  const int RB = cdiv(N, 64);          // 157 row blocks
  const int nGrp = cdiv(RB, 8);        // 20 groups
  for (int t = 0; t < TT; t++) {
    const __bf16* Hbt = hist + (size_t)t * S;
    __bf16* Hbn = hist + (size_t)(t + 1) * S;
    const __bf16* Yat = Ya + (size_t)t * N * 16;
    k_mm<0><<<64 * nGrp, 256, 0, stream>>>(Hbt, WzrP, nullptr, nullptr, Yat, WyZR,
                                           nullptr, Zbf, Rbf, N, RB);
    k_mm<1><<<32 * nGrp, 256, 0, stream>>>(Hbt, WhP, Rbf, Zbf, Yat, WyH,
                                           nullptr, Hbn, nullptr, N, RB);
  }

  // H_accum = sum_t p_t H_{t+1}; head
  k_acc<<<cdiv(N * 64, TPB), TPB, 0, stream>>>(hist, probs, accO, accRelu, N);
  k_mm<2><<<16 * nGrp, 256, 0, stream>>>(accRelu, W1P, nullptr, nullptr, Ya, Wy1,
                                         T1, nullptr, nullptr, N, RB);
  k_head2<<<cdiv(N * 12, TPB), TPB, 0, stream>>>(T1, W2, b2, out0, N);
}

// Round 9
// 966.110 us; speedup vs baseline: 2.1149x; 1.0696x over previous
//
#include <hip/hip_runtime.h>
#include <math.h>

// F=4, T=12, C=512, HID=256, OUT=12
#define NF 48
#define TT 12

typedef __bf16 v8bf __attribute__((ext_vector_type(8)));
typedef float v16f __attribute__((ext_vector_type(16)));

// ---------------- small prep kernels ----------------

__global__ void k_init_deg(float* __restrict__ deg, int n) {
  int i = blockIdx.x * blockDim.x + threadIdx.x;
  if (i < n) deg[i] = 1.0f;
}

__global__ void k_scatter_deg(const int* __restrict__ dst, const float* __restrict__ w,
                              float* __restrict__ deg, int e) {
  int i = blockIdx.x * blockDim.x + threadIdx.x;
  if (i < e) atomicAdd(&deg[dst[i]], w[i]);
}

__global__ void k_dinv(const float* __restrict__ deg, float* __restrict__ dinv, int n) {
  int i = blockIdx.x * blockDim.x + threadIdx.x;
  if (i < n) dinv[i] = rsqrtf(fmaxf(deg[i], 1e-12f));
}

__global__ void k_zeroi(int* __restrict__ p, int n) {
  int i = blockIdx.x * blockDim.x + threadIdx.x;
  if (i < n) p[i] = 0;
}

// ---------------- CSR build (by dst) ----------------

__global__ void k_count(const int* __restrict__ dst, int* __restrict__ cnt, int e) {
  int i = blockIdx.x * blockDim.x + threadIdx.x;
  if (i < e) atomicAdd(&cnt[dst[i]], 1);
}

__global__ void k_scan(const int* __restrict__ cnt, int* __restrict__ offs, int n) {
  __shared__ int s[1024];
  __shared__ int carry;
  int tid = threadIdx.x;
  if (tid == 0) carry = 0;
  __syncthreads();
  for (int base = 0; base < n; base += 1024) {
    int v = (base + tid < n) ? cnt[base + tid] : 0;
    s[tid] = v;
    __syncthreads();
    for (int off = 1; off < 1024; off <<= 1) {
      int t = 0;
      if (tid >= off) t = s[tid - off];
      __syncthreads();
      s[tid] += t;
      __syncthreads();
    }
    if (base + tid < n) offs[base + tid] = carry + s[tid] - v;
    __syncthreads();
    if (tid == 0) carry += s[1023];
    __syncthreads();
  }
  if (tid == 0) offs[n] = carry;
}

__global__ void k_place(const int* __restrict__ src, const int* __restrict__ dst,
                        const float* __restrict__ w, const int* __restrict__ offs,
                        int* __restrict__ fill, int* __restrict__ csrc,
                        float* __restrict__ cw, int e) {
  int i = blockIdx.x * blockDim.x + threadIdx.x;
  if (i >= e) return;
  int d = dst[i];
  int p = offs[d] + atomicAdd(&fill[d], 1);
  csrc[p] = src[i];
  cw[p] = w[i];
}

__global__ void k_gather(const int* __restrict__ offs, const int* __restrict__ csrc,
                         const float* __restrict__ cw, const float* __restrict__ dinv,
                         const float* __restrict__ x, float* __restrict__ Y, int n) {
  int tg = blockIdx.x * blockDim.x + threadIdx.x;
  if (tg >= n * 12) return;
  int i = tg / 12, q = tg % 12;
  float di = dinv[i];
  const float4* x4 = (const float4*)x;
  float4 sv = x4[(size_t)i * 12 + q];
  float ax = di * sv.x, ay = di * sv.y, az = di * sv.z, aw = di * sv.w;
  int e1 = offs[i + 1];
  for (int e = offs[i]; e < e1; e++) {
    int s = csrc[e];
    float wv = cw[e] * dinv[s];
    float4 xv = x4[(size_t)s * 12 + q];
    ax = fmaf(wv, xv.x, ax); ay = fmaf(wv, xv.y, ay);
    az = fmaf(wv, xv.z, az); aw = fmaf(wv, xv.w, aw);
  }
  float4 o = make_float4(di * ax, di * ay, di * az, di * aw);
  ((float4*)Y)[(size_t)i * 12 + q] = o;
}

// ---------------- weight prep: pack into swizzled 128-col tiles ----------------
// layout: [n/128][k/32][ row=n%128 ][ chunk(16B)^(row&3) ][ e ]   (verified R7/R8)
__device__ __forceinline__ size_t packIdx128(int n, int k) {
  int row = n & 127;
  int c = (k & 31) >> 3;
  return (size_t)(n >> 7) * (128 * 512) + (size_t)(k >> 5) * (128 * 32) +
         (size_t)row * 32 + (size_t)((c ^ (row & 3)) << 3) + (k & 7);
}

__global__ void k_t_zr(const float* __restrict__ Wzl, const float* __restrict__ Wrl,
                       __bf16* __restrict__ WT) {
  int idx = blockIdx.x * blockDim.x + threadIdx.x;
  if (idx >= 1024 * 512) return;
  int n = idx >> 9, k = idx & 511;
  float v = (n < 512) ? Wzl[(512 + k) * 512 + n] : Wrl[(512 + k) * 512 + (n - 512)];
  WT[packIdx128(n, k)] = (__bf16)v;
}

__global__ void k_t_h(const float* __restrict__ Whl, __bf16* __restrict__ WT) {
  int idx = blockIdx.x * blockDim.x + threadIdx.x;
  if (idx >= 512 * 512) return;
  int n = idx >> 9, k = idx & 511;
  WT[packIdx128(n, k)] = (__bf16)Whl[(512 + k) * 512 + n];
}

__global__ void k_t_1(const float* __restrict__ W1, __bf16* __restrict__ WT) {
  int idx = blockIdx.x * blockDim.x + threadIdx.x;
  if (idx >= 256 * 512) return;
  int n = idx >> 9, k = idx & 511;
  WT[packIdx128(n, k)] = (__bf16)W1[k * 256 + n];
}

__global__ void k_build_eff(const float* __restrict__ Wg, const float* __restrict__ Wl,
                            const float* __restrict__ bg, const float* __restrict__ bl,
                            float* __restrict__ Weff, float* __restrict__ beff,
                            int ostride, int ooff) {
  int idx = blockIdx.x * blockDim.x + threadIdx.x;
  if (idx >= 5 * 512) return;
  int r = idx / 512, c = idx % 512;
  float s = 0.f;
  if (r < 4) {
    for (int k = 0; k < 512; k++) s += Wg[r * 512 + k] * Wl[k * 512 + c];
    Weff[r * ostride + ooff + c] = s;
  } else {
    for (int k = 0; k < 512; k++) s += bg[k] * Wl[k * 512 + c];
    beff[ooff + c] = s + bl[c];
  }
}

__global__ void k_softmax_att(const float* __restrict__ att, float* __restrict__ probs) {
  if (blockIdx.x == 0 && threadIdx.x == 0) {
    float m = -1e30f;
    for (int t = 0; t < TT; t++) m = fmaxf(m, att[t]);
    float e[TT], s = 0.f;
    for (int t = 0; t < TT; t++) { e[t] = expf(att[t] - m); s += e[t]; }
    for (int t = 0; t < TT; t++) probs[t] = e[t] / s;
  }
}

// Wy mini-tiles [n/128][row][k<16]: rows 0..3 = Weff, row4 = beff, rest 0.
__global__ void k_wy(const float* __restrict__ Weff, const float* __restrict__ beff,
                     __bf16* __restrict__ out, int Nout) {
  int idx = blockIdx.x * blockDim.x + threadIdx.x;
  if (idx >= Nout * 16) return;
  int n = idx >> 4, k = idx & 15;
  float v = 0.f;
  if (k < 4) v = Weff ? Weff[k * Nout + n] : 0.f;
  else if (k == 4) v = beff[n];
  out[(size_t)(n >> 7) * 2048 + (size_t)(n & 127) * 16 + k] = (__bf16)v;
}

// Ya[t][n][16]: cols 0..3 = Y[n, f, t], col4 = 1, rest 0.
__global__ void k_ya(const float* __restrict__ Y, __bf16* __restrict__ out, int n) {
  int idx = blockIdx.x * blockDim.x + threadIdx.x;
  if (idx >= TT * n * 16) return;
  int t = idx / (n * 16);
  int r = idx % (n * 16);
  int nn = r >> 4, k = r & 15;
  float v = 0.f;
  if (k < 4) v = Y[(size_t)nn * NF + k * TT + t];
  else if (k == 4) v = 1.f;
  out[idx] = (__bf16)v;
}

// ---------------- MFMA GEMM: 64x128 tile, 32x32x16, dbuf LDS, 1 barrier/iter ----------------
// 4 waves 2x2 over (64 rows, 128 cols). BK=32, 16 fully-unrolled iterations,
// double-buffered LDS (store k+1 to buf (k+1)&1 while computing buf k&1),
// named staging regs (no scratch). Y@Weff+beff folded as one extra K=16 mfma.
// bf16 outputs staged via LDS for coalesced dwordx4 stores; MODE1 z/hold loads
// are row-linear coalesced after the LDS round-trip.
template <int MODE>
__global__ __launch_bounds__(256, 4) void k_mm(
    const __bf16* __restrict__ Abf, const __bf16* __restrict__ Bp,
    const __bf16* __restrict__ Rbf, const __bf16* __restrict__ Zbf,
    const __bf16* __restrict__ Ay, const __bf16* __restrict__ Wy,
    float* __restrict__ Ofp, __bf16* __restrict__ Obf, __bf16* __restrict__ ObfR,
    int M, int RB) {
  constexpr int CB = (MODE == 0) ? 8 : (MODE == 1) ? 4 : 2;
  constexpr int BUFS = (MODE == 1) ? 8192 : 6144;  // elems per LDS buffer
  __shared__ __bf16 smem[(MODE == 1) ? 16384 : 12288];

  int s = blockIdx.x;
  int grp = 8 * CB;
  int local = s % grp;
  int rowblk = (s / grp) * 8 + (local & 7);
  int colblk = local >> 3;
  if (rowblk >= RB) return;
  const int row0 = rowblk * 64;

  const int tid = threadIdx.x;
  const int lane = tid & 63, w = tid >> 6;
  const int wr = (w >> 1) * 32, wc = (w & 1) * 64;
  const int l31 = lane & 31, lh = lane >> 5;

  const int ar = tid >> 2, ac = tid & 3;
  const __bf16* At = Abf + (size_t)(row0 + ar) * 512 + ac * 8;
  const __bf16* Rt = Rbf + (size_t)(row0 + ar) * 512 + ac * 8;  // MODE1 only
  const __bf16* Bt = Bp + (size_t)colblk * (128 * 512);
  const int aoff = ar * 32 + ((ac ^ (ar & 3)) << 3);

  v16f acc[2];
#pragma unroll
  for (int j = 0; j < 2; j++)
#pragma unroll
    for (int q = 0; q < 16; q++) acc[j][q] = 0.f;

  uint4 ra, rr, rb0, rb1;
  rr = make_uint4(0, 0, 0, 0);

  auto gload = [&](int kt) {
    ra = *(const uint4*)(At + kt * 32);
    if constexpr (MODE == 1) rr = *(const uint4*)(Rt + kt * 32);
    rb0 = *(const uint4*)(Bt + (size_t)kt * 4096 + (size_t)tid * 8);
    rb1 = *(const uint4*)(Bt + (size_t)kt * 4096 + (size_t)(256 + tid) * 8);
  };
  auto lstore = [&](int buf) {
    __bf16* base = smem + buf * BUFS;
    *(uint4*)&base[aoff] = ra;
    if constexpr (MODE == 1) *(uint4*)&base[6144 + aoff] = rr;
    *(uint4*)&base[2048 + (size_t)tid * 8] = rb0;
    *(uint4*)&base[2048 + (size_t)(256 + tid) * 8] = rb1;
  };
  auto compute = [&](int buf) {
    const __bf16* base = smem + buf * BUFS;
#pragma unroll
    for (int ks = 0; ks < 2; ks++) {
      int kc = ks * 2 + lh;
      int fr = wr + l31;
      v8bf a = *(const v8bf*)&base[fr * 32 + ((kc ^ (fr & 3)) << 3)];
      if constexpr (MODE == 1) {
        v8bf r = *(const v8bf*)&base[6144 + fr * 32 + ((kc ^ (fr & 3)) << 3)];
#pragma unroll
        for (int q = 0; q < 8; q++) a[q] = (__bf16)((float)a[q] * (float)r[q]);
      }
#pragma unroll
      for (int ni = 0; ni < 2; ni++) {
        int fc = wc + ni * 32 + l31;
        v8bf b = *(const v8bf*)&base[2048 + fc * 32 + ((kc ^ (fc & 3)) << 3)];
        acc[ni] = __builtin_amdgcn_mfma_f32_32x32x16_bf16(a, b, acc[ni], 0, 0, 0);
      }
    }
  };

  gload(0);
  lstore(0);
  gload(1);
  __syncthreads();
#pragma unroll
  for (int kt = 0; kt < 16; kt++) {
    if (kt < 15) lstore((kt + 1) & 1);   // writes the OTHER buffer
    if (kt < 14) gload(kt + 2);          // in-flight across the barrier
    compute(kt & 1);
    if (kt < 15) __syncthreads();
  }

  // ---- extra K=16 mfma: + Ay(Y_t|1) @ Wy(Weff|beff)   (uses buf0 region)
  {
    int row = tid >> 1, half = tid & 1;
    if (tid < 128)
      *(uint4*)&smem[row * 16 + half * 8] =
          *(const uint4*)(Ay + (size_t)(row0 + row) * 16 + half * 8);
    *(uint4*)&smem[2048 + row * 16 + half * 8] =
        *(const uint4*)(Wy + (size_t)colblk * 2048 + (size_t)row * 16 + half * 8);
  }
  __syncthreads();
  {
    v8bf a = *(const v8bf*)&smem[(wr + l31) * 16 + lh * 8];
#pragma unroll
    for (int ni = 0; ni < 2; ni++) {
      v8bf b = *(const v8bf*)&smem[2048 + (wc + ni * 32 + l31) * 16 + lh * 8];
      acc[ni] = __builtin_amdgcn_mfma_f32_32x32x16_bf16(a, b, acc[ni], 0, 0, 0);
    }
  }
  __syncthreads();  // before reusing smem as output stage

  // ---- epilogue. C layout (32x32): col=lane&31, row=(reg&3)+8*(reg>>2)+4*lh
  if constexpr (MODE == 2) {
#pragma unroll
    for (int ni = 0; ni < 2; ni++) {
      int cl = wc + ni * 32 + l31;
#pragma unroll
      for (int reg = 0; reg < 16; reg++) {
        int rg = row0 + wr + (reg & 3) + ((reg >> 2) << 3) + (lh << 2);
        if (rg >= M) continue;
        Ofp[(size_t)rg * 256 + colblk * 128 + cl] = fmaxf(acc[ni][reg], 0.f);
      }
    }
  } else if constexpr (MODE == 0) {
#pragma unroll
    for (int ni = 0; ni < 2; ni++) {
      int cl = wc + ni * 32 + l31;
#pragma unroll
      for (int reg = 0; reg < 16; reg++) {
        int lr = wr + (reg & 3) + ((reg >> 2) << 3) + (lh << 2);
        smem[lr * 128 + cl] = (__bf16)(1.f / (1.f + expf(-acc[ni][reg])));
      }
    }
    __syncthreads();
    int row = tid >> 2, seg = (tid & 3) * 32;
    int rg = row0 + row;
    if (rg < M) {
      __bf16* dst = (colblk < 4) ? Obf : ObfR;
      int cof = (colblk & 3) * 128;
#pragma unroll
      for (int q = 0; q < 4; q++) {
        uint4 v = *(const uint4*)&smem[row * 128 + seg + q * 8];
        *(uint4*)(dst + (size_t)rg * 512 + cof + seg + q * 8) = v;
      }
    }
  } else {  // MODE 1: ht via fp32 LDS; z/hold coalesced row-linear
    float* smemF = (float*)smem;
#pragma unroll
    for (int ni = 0; ni < 2; ni++) {
      int cl = wc + ni * 32 + l31;
#pragma unroll
      for (int reg = 0; reg < 16; reg++) {
        int lr = wr + (reg & 3) + ((reg >> 2) << 3) + (lh << 2);
        smemF[lr * 128 + cl] = tanhf(acc[ni][reg]);
      }
    }
    __syncthreads();
    int row = tid >> 2, seg = (tid & 3) * 32;
    int rg = row0 + row;
    if (rg < M) {
      int cg0 = colblk * 128 + seg;
#pragma unroll
      for (int q = 0; q < 4; q++) {
        v8bf z8 = *(const v8bf*)(Zbf + (size_t)rg * 512 + cg0 + q * 8);
        v8bf h8 = *(const v8bf*)(Abf + (size_t)rg * 512 + cg0 + q * 8);
        v8bf o;
#pragma unroll
        for (int j = 0; j < 8; j++) {
          float z = (float)z8[j];
          float ht = smemF[row * 128 + seg + q * 8 + j];
          o[j] = (__bf16)(z * (float)h8[j] + (1.f - z) * ht);
        }
        *(v8bf*)(Obf + (size_t)rg * 512 + cg0 + q * 8) = o;
      }
    }
  }
}

// acc[i,c] = sum_t probs[t] * hist[t+1][i,c];  accRelu = bf16(relu(acc))
__global__ void k_acc(const __bf16* __restrict__ hist, const float* __restrict__ probs,
                      float* __restrict__ acc, __bf16* __restrict__ accRelu, int n) {
  int idx = blockIdx.x * blockDim.x + threadIdx.x;
  if (idx >= n * 64) return;
  size_t off = (size_t)idx * 8;
  size_t S = (size_t)n * 512;
  float s[8] = {0, 0, 0, 0, 0, 0, 0, 0};
#pragma unroll
  for (int t = 0; t < TT; t++) {
    float p = probs[t];
    v8bf h = *(const v8bf*)(hist + (size_t)(t + 1) * S + off);
#pragma unroll
    for (int j = 0; j < 8; j++) s[j] = fmaf(p, (float)h[j], s[j]);
  }
  *(float4*)(acc + off) = make_float4(s[0], s[1], s[2], s[3]);
  *(float4*)(acc + off + 4) = make_float4(s[4], s[5], s[6], s[7]);
  v8bf rl;
#pragma unroll
  for (int j = 0; j < 8; j++) rl[j] = (__bf16)fmaxf(s[j], 0.f);
  *(v8bf*)(accRelu + off) = rl;
}

__global__ void k_head2(const float* __restrict__ T1, const float* __restrict__ W2,
                        const float* __restrict__ b2, float* __restrict__ out0, int M) {
  int idx = blockIdx.x * blockDim.x + threadIdx.x;
  if (idx >= M * 12) return;
  int i = idx / 12, c = idx % 12;
  const float* tr = T1 + (size_t)i * 256;
  float s = b2[c];
  for (int k = 0; k < 256; k++) s = fmaf(tr[k], W2[k * 12 + c], s);
  out0[idx] = s;
}

// ---------------- launch ----------------

extern "C" void kernel_launch(void* const* d_in, const int* in_sizes, int n_in,
                              void* d_out, int out_size, void* d_ws, size_t ws_size,
                              hipStream_t stream) {
  const float* x   = (const float*)d_in[0];
  const int*   ei  = (const int*)d_in[1];
  const float* ea  = (const float*)d_in[2];
  const float* att = (const float*)d_in[3];
  const float* Wzg = (const float*)d_in[4];  const float* bzg = (const float*)d_in[5];
  const float* Wzl = (const float*)d_in[6];  const float* bzl = (const float*)d_in[7];
  const float* Wrg = (const float*)d_in[8];  const float* brg = (const float*)d_in[9];
  const float* Wrl = (const float*)d_in[10]; const float* brl = (const float*)d_in[11];
  const float* Whg = (const float*)d_in[12]; const float* bhg = (const float*)d_in[13];
  const float* Whl = (const float*)d_in[14]; const float* bhl = (const float*)d_in[15];
  const float* W1  = (const float*)d_in[16]; const float* b1  = (const float*)d_in[17];
  const float* W2  = (const float*)d_in[18]; const float* b2  = (const float*)d_in[19];

  const int N = in_sizes[0] / NF;
  const int E = in_sizes[1] / 2;
  const int* srcI = ei;
  const int* dstI = ei + E;

  float* out0 = (float*)d_out;                   // [N,12]
  float* accO = (float*)d_out + (size_t)N * 12;  // [N,512] = H_accum (output 1)

  char* wp = (char*)d_ws;
  auto carve = [&](size_t bytes) -> void* {
    void* p = (void*)wp;
    wp += (bytes + 255) & ~(size_t)255;
    return p;
  };
  float*  deg     = (float*)carve((size_t)N * 4);
  float*  dinv    = (float*)carve((size_t)N * 4);
  float*  probs   = (float*)carve(64);
  float*  Y       = (float*)carve((size_t)N * NF * 4);
  __bf16* WzrP    = (__bf16*)carve((size_t)1024 * 512 * 2);
  __bf16* WhP     = (__bf16*)carve((size_t)512 * 512 * 2);
  __bf16* W1P     = (__bf16*)carve((size_t)256 * 512 * 2);
  float*  Wzr_eff = (float*)carve((size_t)4 * 1024 * 4);
  float*  bzr_eff = (float*)carve((size_t)1024 * 4);
  float*  Wh_eff  = (float*)carve((size_t)4 * 512 * 4);
  float*  bh_eff  = (float*)carve((size_t)512 * 4);
  __bf16* hist    = (__bf16*)carve((size_t)(TT + 1) * N * 512 * 2);  // H_0..H_12 bf16
  __bf16* Zbf     = (__bf16*)carve((size_t)N * 512 * 2);
  __bf16* Rbf     = (__bf16*)carve((size_t)N * 512 * 2);
  __bf16* accRelu = (__bf16*)carve((size_t)N * 512 * 2);
  float*  T1      = (float*)carve((size_t)N * 256 * 4);
  __bf16* Ya      = (__bf16*)carve((size_t)TT * N * 16 * 2);
  __bf16* WyZR    = (__bf16*)carve((size_t)1024 * 16 * 2);
  __bf16* WyH     = (__bf16*)carve((size_t)512 * 16 * 2);
  __bf16* Wy1     = (__bf16*)carve((size_t)256 * 16 * 2);
  int*    cnt     = (int*)carve((size_t)2 * N * 4);  // cnt[N] + fill[N] contiguous
  int*    fill    = cnt + N;
  int*    offs    = (int*)carve((size_t)(N + 1) * 4);
  int*    csrc    = (int*)carve((size_t)E * 4);
  float*  cw      = (float*)carve((size_t)E * 4);
  (void)carve(512 * 1024);  // tail pad: OOB tile reads stay inside ws
  (void)ws_size; (void)n_in; (void)out_size;

  const int TPB = 256;
  auto cdiv = [](int a, int b) { return (a + b - 1) / b; };
  const size_t S = (size_t)N * 512;

  // degree + normalization
  k_init_deg<<<cdiv(N, TPB), TPB, 0, stream>>>(deg, N);
  k_scatter_deg<<<cdiv(E, TPB), TPB, 0, stream>>>(dstI, ea, deg, E);
  k_dinv<<<cdiv(N, TPB), TPB, 0, stream>>>(deg, dinv, N);

  // CSR by dst, then gather Y = Ahat @ X
  k_zeroi<<<cdiv(2 * N, TPB), TPB, 0, stream>>>(cnt, 2 * N);
  k_count<<<cdiv(E, TPB), TPB, 0, stream>>>(dstI, cnt, E);
  k_scan<<<1, 1024, 0, stream>>>(cnt, offs, N);
  k_place<<<cdiv(E, TPB), TPB, 0, stream>>>(srcI, dstI, ea, offs, fill, csrc, cw, E);
  k_gather<<<cdiv(N * 12, TPB), TPB, 0, stream>>>(offs, csrc, cw, dinv, x, Y, N);

  // weight prep
  k_t_zr<<<cdiv(1024 * 512, TPB), TPB, 0, stream>>>(Wzl, Wrl, WzrP);
  k_t_h<<<cdiv(512 * 512, TPB), TPB, 0, stream>>>(Whl, WhP);
  k_t_1<<<cdiv(256 * 512, TPB), TPB, 0, stream>>>(W1, W1P);
  k_build_eff<<<cdiv(5 * 512, TPB), TPB, 0, stream>>>(Wzg, Wzl, bzg, bzl, Wzr_eff, bzr_eff, 1024, 0);
  k_build_eff<<<cdiv(5 * 512, TPB), TPB, 0, stream>>>(Wrg, Wrl, brg, brl, Wzr_eff, bzr_eff, 1024, 512);
  k_build_eff<<<cdiv(5 * 512, TPB), TPB, 0, stream>>>(Whg, Whl, bhg, bhl, Wh_eff, bh_eff, 512, 0);
  k_softmax_att<<<1, 64, 0, stream>>>(att, probs);
  k_wy<<<cdiv(1024 * 16, TPB), TPB, 0, stream>>>(Wzr_eff, bzr_eff, WyZR, 1024);
  k_wy<<<cdiv(512 * 16, TPB), TPB, 0, stream>>>(Wh_eff, bh_eff, WyH, 512);
  k_wy<<<cdiv(256 * 16, TPB), TPB, 0, stream>>>(nullptr, b1, Wy1, 256);
  k_ya<<<cdiv(TT * N * 16, TPB), TPB, 0, stream>>>(Y, Ya, N);

  // hist slot 0 = H_0 = 0
  k_zeroi<<<cdiv(N * 256, TPB), TPB, 0, stream>>>((int*)hist, N * 256);

  const int RB = cdiv(N, 64);          // 157 row blocks
  const int nGrp = cdiv(RB, 8);        // 20 groups
  for (int t = 0; t < TT; t++) {
    const __bf16* Hbt = hist + (size_t)t * S;
    __bf16* Hbn = hist + (size_t)(t + 1) * S;
    const __bf16* Yat = Ya + (size_t)t * N * 16;
    k_mm<0><<<64 * nGrp, 256, 0, stream>>>(Hbt, WzrP, nullptr, nullptr, Yat, WyZR,
                                           nullptr, Zbf, Rbf, N, RB);
    k_mm<1><<<32 * nGrp, 256, 0, stream>>>(Hbt, WhP, Rbf, Zbf, Yat, WyH,
                                           nullptr, Hbn, nullptr, N, RB);
  }

  // H_accum = sum_t p_t H_{t+1}; head
  k_acc<<<cdiv(N * 64, TPB), TPB, 0, stream>>>(hist, probs, accO, accRelu, N);
  k_mm<2><<<16 * nGrp, 256, 0, stream>>>(accRelu, W1P, nullptr, nullptr, Ya, Wy1,
                                         T1, nullptr, nullptr, N, RB);
  k_head2<<<cdiv(N * 12, TPB), TPB, 0, stream>>>(T1, W2, b2, out0, N);
}